// Round 2
// baseline (3990.326 us; speedup 1.0000x reference)
//
#include <hip/hip_runtime.h>

#define N_NODES 50000
#define N_EDGES 500000
#define F_IN    112
#define F1      336
#define F2      168
#define NGRAPH  256

// ---------------- degree / dinv ----------------
__global__ void k_init_deg(float* deg, int n) {
    int i = blockIdx.x * blockDim.x + threadIdx.x;
    if (i < n) deg[i] = 1.0f;   // self-loop contributes 1
}
__global__ void k_count_deg(const int* __restrict__ dst, float* deg, int e) {
    int i = blockIdx.x * blockDim.x + threadIdx.x;
    if (i < e) atomicAdd(&deg[dst[i]], 1.0f);
}
__global__ void k_rsqrt(float* deg, int n) {
    int i = blockIdx.x * blockDim.x + threadIdx.x;
    if (i < n) deg[i] = rsqrtf(deg[i]);
}

// ---------------- fp32 tiled GEMM: C[M,N] = A[M,K] @ B[K,N] ----------------
// TM=TN=64, 256 threads, 4x4 micro-tile per thread.
template<int TK>
__global__ __launch_bounds__(256) void k_gemm(const float* __restrict__ A,
                                              const float* __restrict__ Bm,
                                              float* __restrict__ C,
                                              int M, int K, int N) {
    __shared__ float As[64][TK + 1];   // [m][k], +1 pad
    __shared__ float Bs[TK][64];       // [k][n]
    const int tid = threadIdx.x;
    const int tx = tid & 15;           // col group 0..15
    const int ty = tid >> 4;           // row group 0..15
    const int row0 = blockIdx.y * 64;
    const int col0 = blockIdx.x * 64;

    float acc[4][4] = {};

    for (int k0 = 0; k0 < K; k0 += TK) {
        #pragma unroll
        for (int i = 0; i < (64 * TK) / 256; ++i) {
            int idx = tid + i * 256;
            int m = idx / TK, k = idx % TK;
            int gr = row0 + m, gk = k0 + k;
            As[m][k] = (gr < M && gk < K) ? A[(long)gr * K + gk] : 0.0f;
        }
        #pragma unroll
        for (int i = 0; i < (64 * TK) / 256; ++i) {
            int idx = tid + i * 256;
            int k = idx >> 6, n = idx & 63;
            int gk = k0 + k, gc = col0 + n;
            Bs[k][n] = (gk < K && gc < N) ? Bm[(long)gk * N + gc] : 0.0f;
        }
        __syncthreads();
        #pragma unroll
        for (int k = 0; k < TK; ++k) {
            float a0 = As[ty * 4 + 0][k];
            float a1 = As[ty * 4 + 1][k];
            float a2 = As[ty * 4 + 2][k];
            float a3 = As[ty * 4 + 3][k];
            float4 b = *(const float4*)&Bs[k][tx * 4];
            acc[0][0] += a0 * b.x; acc[0][1] += a0 * b.y; acc[0][2] += a0 * b.z; acc[0][3] += a0 * b.w;
            acc[1][0] += a1 * b.x; acc[1][1] += a1 * b.y; acc[1][2] += a1 * b.z; acc[1][3] += a1 * b.w;
            acc[2][0] += a2 * b.x; acc[2][1] += a2 * b.y; acc[2][2] += a2 * b.z; acc[2][3] += a2 * b.w;
            acc[3][0] += a3 * b.x; acc[3][1] += a3 * b.y; acc[3][2] += a3 * b.z; acc[3][3] += a3 * b.w;
        }
        __syncthreads();
    }

    #pragma unroll
    for (int i = 0; i < 4; ++i) {
        int gr = row0 + ty * 4 + i;
        if (gr >= M) continue;
        #pragma unroll
        for (int j = 0; j < 4; ++j) {
            int gc = col0 + tx * 4 + j;
            if (gc < N) C[(long)gr * N + gc] = acc[i][j];
        }
    }
}

// ---------------- aggregation (all 4-wide over features) ----------------
// A[v] = H[v]*dinv[v]^2  (self-loop term; replaces zero-init)
template<int F>
__global__ void k_init_self(const float* __restrict__ H, float* __restrict__ A,
                            const float* __restrict__ dinv, int n) {
    long i = (long)blockIdx.x * blockDim.x + threadIdx.x;   // in float4 units
    long total = (long)n * (F / 4);
    if (i >= total) return;
    int v = (int)(i / (F / 4));
    float di = dinv[v];
    float s = di * di;
    float4 h = ((const float4*)H)[i];
    float4 r; r.x = h.x * s; r.y = h.y * s; r.z = h.z * s; r.w = h.w * s;
    ((float4*)A)[i] = r;
}

// A[dst] += H[src] * dinv[src]*dinv[dst], one thread per (edge, 4 features)
template<int F>
__global__ void k_agg_edges(const float* __restrict__ H, float* __restrict__ A,
                            const int* __restrict__ src, const int* __restrict__ dst,
                            const float* __restrict__ dinv) {
    long i = (long)blockIdx.x * blockDim.x + threadIdx.x;   // (edge, feat-quad)
    const int FQ = F / 4;
    long total = (long)N_EDGES * FQ;
    if (i >= total) return;
    int e = (int)(i / FQ);                 // compile-time FQ -> magic mul
    int q = (int)(i - (long)e * FQ);
    int s = src[e], d = dst[e];
    float norm = dinv[s] * dinv[d];
    float4 h = *(const float4*)&H[(long)s * F + q * 4];
    float* a = &A[(long)d * F + q * 4];
    atomicAdd(a + 0, h.x * norm);
    atomicAdd(a + 1, h.y * norm);
    atomicAdd(a + 2, h.z * norm);
    atomicAdd(a + 3, h.w * norm);
}

// A = relu(A + b)
template<int F>
__global__ void k_bias_relu(float* __restrict__ A, const float* __restrict__ b, int n) {
    long i = (long)blockIdx.x * blockDim.x + threadIdx.x;   // float4 units
    long total = (long)n * (F / 4);
    if (i >= total) return;
    int q = (int)(i % (F / 4));
    float4 bb = ((const float4*)b)[q];
    float4 a = ((float4*)A)[i];
    a.x = fmaxf(a.x + bb.x, 0.0f);
    a.y = fmaxf(a.y + bb.y, 0.0f);
    a.z = fmaxf(a.z + bb.z, 0.0f);
    a.w = fmaxf(a.w + bb.w, 0.0f);
    ((float4*)A)[i] = a;
}

// ---------------- global max pool ----------------
__global__ void k_zero(float* p, int n) {
    int i = blockIdx.x * blockDim.x + threadIdx.x;
    if (i < n) p[i] = 0.0f;
}
// values are post-ReLU (>=0): int-bit compare == float compare, init 0 is identity
template<int F>
__global__ void k_pool_max(const float* __restrict__ H, const int* __restrict__ batch,
                           float* __restrict__ g, int n) {
    long i = (long)blockIdx.x * blockDim.x + threadIdx.x;   // (node, feat-quad)
    const int FQ = F / 4;
    long total = (long)n * FQ;
    if (i >= total) return;
    int v = (int)(i / FQ);
    int q = (int)(i - (long)v * FQ);
    int b = batch[v];
    float4 h = *(const float4*)&H[(long)v * F + q * 4];
    int* gp = (int*)&g[(long)b * F + q * 4];
    atomicMax(gp + 0, __float_as_int(h.x));
    atomicMax(gp + 1, __float_as_int(h.y));
    atomicMax(gp + 2, __float_as_int(h.z));
    atomicMax(gp + 3, __float_as_int(h.w));
}

// ---------------- MLP head ----------------
__global__ __launch_bounds__(128) void k_mlp_head(const float* __restrict__ g,
        const float* __restrict__ Wg, const float* __restrict__ bg,
        const float* __restrict__ Wf, const float* __restrict__ bf,
        const float* __restrict__ Wo, const float* __restrict__ bo,
        float* __restrict__ out) {
    __shared__ float s0[F2];   // 168
    __shared__ float s1[84];
    __shared__ float s2[42];
    int gi = blockIdx.x;
    int t = threadIdx.x;
    for (int i = t; i < F2; i += blockDim.x) s0[i] = g[(long)gi * F2 + i];
    __syncthreads();
    if (t < 84) {
        float a = bg[t];
        #pragma unroll 4
        for (int k = 0; k < F2; ++k) a += s0[k] * Wg[k * 84 + t];
        s1[t] = fmaxf(a, 0.0f);
    }
    __syncthreads();
    if (t < 42) {
        float a = bf[t];
        #pragma unroll 4
        for (int k = 0; k < 84; ++k) a += s1[k] * Wf[k * 42 + t];
        s2[t] = fmaxf(a, 0.0f);
    }
    __syncthreads();
    if (t == 0) {
        float a = bo[0];
        for (int k = 0; k < 42; ++k) a += s2[k] * Wo[k];
        out[gi] = a;
    }
}

extern "C" void kernel_launch(void* const* d_in, const int* in_sizes, int n_in,
                              void* d_out, int out_size, void* d_ws, size_t ws_size,
                              hipStream_t stream) {
    const float* x   = (const float*)d_in[0];
    const int*   ei  = (const int*)d_in[1];
    const int*   bat = (const int*)d_in[2];
    const float* W1  = (const float*)d_in[3];
    const float* b1  = (const float*)d_in[4];
    const float* W2  = (const float*)d_in[5];
    const float* b2  = (const float*)d_in[6];
    const float* Wg  = (const float*)d_in[7];
    const float* bg  = (const float*)d_in[8];
    const float* Wf  = (const float*)d_in[9];
    const float* bf  = (const float*)d_in[10];
    const float* Wo  = (const float*)d_in[11];
    const float* bo  = (const float*)d_in[12];
    float* out = (float*)d_out;

    float* ws   = (float*)d_ws;
    float* dinv = ws;                            // 50000 floats (padded to 64K)
    float* buf1 = ws + (1 << 16);                // 50000*336 floats
    float* buf2 = buf1 + (long)N_NODES * F1;     // 50000*336 floats
    float* g    = buf2 + (long)N_NODES * F1;     // 256*168 floats

    const int* src = ei;
    const int* dst = ei + N_EDGES;

    const int B = 256;
    // degrees -> dinv
    k_init_deg<<<(N_NODES + B - 1) / B, B, 0, stream>>>(dinv, N_NODES);
    k_count_deg<<<(N_EDGES + B - 1) / B, B, 0, stream>>>(dst, dinv, N_EDGES);
    k_rsqrt<<<(N_NODES + B - 1) / B, B, 0, stream>>>(dinv, N_NODES);

    // conv1: H1 = x @ W1
    dim3 gg1((F1 + 63) / 64, (N_NODES + 63) / 64);
    k_gemm<16><<<gg1, 256, 0, stream>>>(x, W1, buf1, N_NODES, F_IN, F1);
    long n1q = (long)N_NODES * (F1 / 4);
    long e1q = (long)N_EDGES * (F1 / 4);
    k_init_self<F1><<<(int)((n1q + B - 1) / B), B, 0, stream>>>(buf1, buf2, dinv, N_NODES);
    k_agg_edges<F1><<<(int)((e1q + B - 1) / B), B, 0, stream>>>(buf1, buf2, src, dst, dinv);
    k_bias_relu<F1><<<(int)((n1q + B - 1) / B), B, 0, stream>>>(buf2, b1, N_NODES);

    // conv2: H2 = out1 @ W2
    dim3 gg2((F2 + 63) / 64, (N_NODES + 63) / 64);
    k_gemm<16><<<gg2, 256, 0, stream>>>(buf2, W2, buf1, N_NODES, F1, F2);
    long n2q = (long)N_NODES * (F2 / 4);
    long e2q = (long)N_EDGES * (F2 / 4);
    k_init_self<F2><<<(int)((n2q + B - 1) / B), B, 0, stream>>>(buf1, buf2, dinv, N_NODES);
    k_agg_edges<F2><<<(int)((e2q + B - 1) / B), B, 0, stream>>>(buf1, buf2, src, dst, dinv);
    k_bias_relu<F2><<<(int)((n2q + B - 1) / B), B, 0, stream>>>(buf2, b2, N_NODES);

    // global max pool
    k_zero<<<(NGRAPH * F2 + B - 1) / B, B, 0, stream>>>(g, NGRAPH * F2);
    k_pool_max<F2><<<(int)((n2q + B - 1) / B), B, 0, stream>>>(buf2, bat, g, N_NODES);

    // MLP head
    k_mlp_head<<<NGRAPH, 128, 0, stream>>>(g, Wg, bg, Wf, bf, Wo, bo, out);
}

// Round 3
// 653.014 us; speedup vs baseline: 6.1106x; 6.1106x over previous
//
#include <hip/hip_runtime.h>

#define N_NODES 50000
#define N_EDGES 500000
#define F_IN    112
#define F1      336
#define F2      168
#define NGRAPH  256
#define SCAN_CHUNK 1024
#define SCAN_BLOCKS ((N_NODES + SCAN_CHUNK - 1) / SCAN_CHUNK)   // 49

// ---------------- small utility kernels ----------------
__global__ void k_zero_int(int* p, int n) {
    int i = blockIdx.x * blockDim.x + threadIdx.x;
    if (i < n) p[i] = 0;
}
__global__ void k_zero_f(float* p, int n) {
    int i = blockIdx.x * blockDim.x + threadIdx.x;
    if (i < n) p[i] = 0.0f;
}
__global__ void k_count_deg(const int* __restrict__ dst, int* __restrict__ dcount, int e) {
    int i = blockIdx.x * blockDim.x + threadIdx.x;
    if (i < e) atomicAdd(&dcount[dst[i]], 1);
}
__global__ void k_dinv(const int* __restrict__ dcount, float* __restrict__ dinv, int n) {
    int i = blockIdx.x * blockDim.x + threadIdx.x;
    if (i < n) dinv[i] = rsqrtf((float)dcount[i] + 1.0f);   // +1 self-loop
}

// ---------------- exclusive scan of dcount -> off (3 kernels) ----------------
__global__ __launch_bounds__(SCAN_CHUNK) void k_scan1(const int* __restrict__ dcount,
                                                      int* __restrict__ off,
                                                      int* __restrict__ partials, int n) {
    __shared__ int s[SCAN_CHUNK];
    int t = threadIdx.x;
    int i = blockIdx.x * SCAN_CHUNK + t;
    int val = (i < n) ? dcount[i] : 0;
    s[t] = val;
    __syncthreads();
    for (int d = 1; d < SCAN_CHUNK; d <<= 1) {
        int x = (t >= d) ? s[t - d] : 0;
        __syncthreads();
        s[t] += x;
        __syncthreads();
    }
    if (i < n) off[i] = s[t] - val;          // exclusive, chunk-local
    if (t == SCAN_CHUNK - 1) partials[blockIdx.x] = s[t];
}
__global__ void k_scan2(int* __restrict__ partials, int* __restrict__ off, int nblk, int n) {
    if (threadIdx.x == 0 && blockIdx.x == 0) {
        int run = 0;
        for (int j = 0; j < nblk; ++j) { int p = partials[j]; partials[j] = run; run += p; }
        off[n] = run;                         // total edge count
    }
}
__global__ __launch_bounds__(SCAN_CHUNK) void k_scan3(int* __restrict__ off,
                                                      const int* __restrict__ partials, int n) {
    int i = blockIdx.x * SCAN_CHUNK + threadIdx.x;
    if (i < n) off[i] += partials[blockIdx.x];
}

// ---------------- scatter edges into dst-sorted CSR ----------------
__global__ void k_scatter(const int* __restrict__ src, const int* __restrict__ dst,
                          const int* __restrict__ off, int* __restrict__ cur,
                          const float* __restrict__ dinv,
                          int* __restrict__ csr_src, float* __restrict__ csr_coef, int e) {
    int i = blockIdx.x * blockDim.x + threadIdx.x;
    if (i >= e) return;
    int s = src[i], d = dst[i];
    int pos = atomicAdd(&cur[d], 1);
    int idx = off[d] + pos;
    csr_src[idx] = s;
    csr_coef[idx] = dinv[s] * dinv[d];
}

// ---------------- aggregation layer 1: out = A_norm @ X  (F_IN=112, float2/lane) ----------------
__global__ __launch_bounds__(256) void k_agg1(const float* __restrict__ X,
                                              const int* __restrict__ off,
                                              const int* __restrict__ csr_src,
                                              const float* __restrict__ csr_coef,
                                              const float* __restrict__ dinv,
                                              float* __restrict__ out) {
    int gw = (blockIdx.x * 256 + threadIdx.x) >> 6;   // wave id = node id
    int lane = threadIdx.x & 63;
    if (gw >= N_NODES) return;
    const int v = gw;
    const int NV = F_IN / 2;                           // 56 active lanes
    int o0 = off[v], o1 = off[v + 1];
    float di = dinv[v];
    float2 acc = {0.0f, 0.0f};
    if (lane < NV) {
        float2 xv = ((const float2*)(X + (long)v * F_IN))[lane];
        float s2 = di * di;
        acc.x = xv.x * s2; acc.y = xv.y * s2;          // self-loop
    }
    for (int i = o0; i < o1; ++i) {
        int s = csr_src[i];
        float c = csr_coef[i];
        if (lane < NV) {
            float2 xs = ((const float2*)(X + (long)s * F_IN))[lane];
            acc.x += c * xs.x; acc.y += c * xs.y;
        }
    }
    if (lane < NV) ((float2*)(out + (long)v * F_IN))[lane] = acc;
}

// ---------------- aggregation layer 2 + bias + relu + max-pool fused ----------------
// out2[v] = relu(sum_{s->v} coef*T[s] + dinv[v]^2*T[v] + b2); g[batch[v]] = max(g, out2[v])
__global__ __launch_bounds__(256) void k_agg2_pool(const float* __restrict__ T,
                                                   const int* __restrict__ off,
                                                   const int* __restrict__ csr_src,
                                                   const float* __restrict__ csr_coef,
                                                   const float* __restrict__ dinv,
                                                   const float* __restrict__ b2,
                                                   const int* __restrict__ batch,
                                                   float* __restrict__ g) {
    int gw = (blockIdx.x * 256 + threadIdx.x) >> 6;
    int lane = threadIdx.x & 63;
    if (gw >= N_NODES) return;
    const int v = gw;
    const int NV = F2 / 4;                             // 42 active lanes
    int o0 = off[v], o1 = off[v + 1];
    float di = dinv[v];
    float4 acc = {0.0f, 0.0f, 0.0f, 0.0f};
    if (lane < NV) {
        float4 tv = ((const float4*)(T + (long)v * F2))[lane];
        float s2 = di * di;
        acc.x = tv.x * s2; acc.y = tv.y * s2; acc.z = tv.z * s2; acc.w = tv.w * s2;
    }
    for (int i = o0; i < o1; ++i) {
        int s = csr_src[i];
        float c = csr_coef[i];
        if (lane < NV) {
            float4 ts = ((const float4*)(T + (long)s * F2))[lane];
            acc.x += c * ts.x; acc.y += c * ts.y; acc.z += c * ts.z; acc.w += c * ts.w;
        }
    }
    if (lane < NV) {
        float4 bb = ((const float4*)b2)[lane];
        acc.x = fmaxf(acc.x + bb.x, 0.0f);
        acc.y = fmaxf(acc.y + bb.y, 0.0f);
        acc.z = fmaxf(acc.z + bb.z, 0.0f);
        acc.w = fmaxf(acc.w + bb.w, 0.0f);
        int b = batch[v];
        int* gp = (int*)(g + (long)b * F2 + lane * 4);
        atomicMax(gp + 0, __float_as_int(acc.x));      // post-relu >= 0: int cmp == float cmp
        atomicMax(gp + 1, __float_as_int(acc.y));
        atomicMax(gp + 2, __float_as_int(acc.z));
        atomicMax(gp + 3, __float_as_int(acc.w));
    }
}

// ---------------- fp32 tiled GEMM: C = A[M,K]@B[K,N] (+bias,relu) ----------------
template<int TK, bool FUSE_BIAS_RELU>
__global__ __launch_bounds__(256) void k_gemm(const float* __restrict__ A,
                                              const float* __restrict__ Bm,
                                              const float* __restrict__ bias,
                                              float* __restrict__ C,
                                              int M, int K, int N) {
    __shared__ float As[64][TK + 1];
    __shared__ float Bs[TK][64];
    const int tid = threadIdx.x;
    const int tx = tid & 15;
    const int ty = tid >> 4;
    const int row0 = blockIdx.y * 64;
    const int col0 = blockIdx.x * 64;

    float acc[4][4] = {};

    for (int k0 = 0; k0 < K; k0 += TK) {
        #pragma unroll
        for (int i = 0; i < (64 * TK) / 256; ++i) {
            int idx = tid + i * 256;
            int m = idx / TK, k = idx % TK;
            int gr = row0 + m, gk = k0 + k;
            As[m][k] = (gr < M && gk < K) ? A[(long)gr * K + gk] : 0.0f;
        }
        #pragma unroll
        for (int i = 0; i < (64 * TK) / 256; ++i) {
            int idx = tid + i * 256;
            int k = idx >> 6, n = idx & 63;
            int gk = k0 + k, gc = col0 + n;
            Bs[k][n] = (gk < K && gc < N) ? Bm[(long)gk * N + gc] : 0.0f;
        }
        __syncthreads();
        #pragma unroll
        for (int k = 0; k < TK; ++k) {
            float a0 = As[ty * 4 + 0][k];
            float a1 = As[ty * 4 + 1][k];
            float a2 = As[ty * 4 + 2][k];
            float a3 = As[ty * 4 + 3][k];
            float4 b = *(const float4*)&Bs[k][tx * 4];
            acc[0][0] += a0 * b.x; acc[0][1] += a0 * b.y; acc[0][2] += a0 * b.z; acc[0][3] += a0 * b.w;
            acc[1][0] += a1 * b.x; acc[1][1] += a1 * b.y; acc[1][2] += a1 * b.z; acc[1][3] += a1 * b.w;
            acc[2][0] += a2 * b.x; acc[2][1] += a2 * b.y; acc[2][2] += a2 * b.z; acc[2][3] += a2 * b.w;
            acc[3][0] += a3 * b.x; acc[3][1] += a3 * b.y; acc[3][2] += a3 * b.z; acc[3][3] += a3 * b.w;
        }
        __syncthreads();
    }

    #pragma unroll
    for (int i = 0; i < 4; ++i) {
        int gr = row0 + ty * 4 + i;
        if (gr >= M) continue;
        #pragma unroll
        for (int j = 0; j < 4; ++j) {
            int gc = col0 + tx * 4 + j;
            if (gc >= N) continue;
            float r = acc[i][j];
            if (FUSE_BIAS_RELU) r = fmaxf(r + bias[gc], 0.0f);
            C[(long)gr * N + gc] = r;
        }
    }
}

// ---------------- MLP head ----------------
__global__ __launch_bounds__(128) void k_mlp_head(const float* __restrict__ g,
        const float* __restrict__ Wg, const float* __restrict__ bg,
        const float* __restrict__ Wf, const float* __restrict__ bf,
        const float* __restrict__ Wo, const float* __restrict__ bo,
        float* __restrict__ out) {
    __shared__ float s0[F2];
    __shared__ float s1[84];
    __shared__ float s2[42];
    int gi = blockIdx.x;
    int t = threadIdx.x;
    for (int i = t; i < F2; i += blockDim.x) s0[i] = g[(long)gi * F2 + i];
    __syncthreads();
    if (t < 84) {
        float a = bg[t];
        #pragma unroll 4
        for (int k = 0; k < F2; ++k) a += s0[k] * Wg[k * 84 + t];
        s1[t] = fmaxf(a, 0.0f);
    }
    __syncthreads();
    if (t < 42) {
        float a = bf[t];
        #pragma unroll 4
        for (int k = 0; k < 84; ++k) a += s1[k] * Wf[k * 42 + t];
        s2[t] = fmaxf(a, 0.0f);
    }
    __syncthreads();
    if (t == 0) {
        float a = bo[0];
        for (int k = 0; k < 42; ++k) a += s2[k] * Wo[k];
        out[gi] = a;
    }
}

extern "C" void kernel_launch(void* const* d_in, const int* in_sizes, int n_in,
                              void* d_out, int out_size, void* d_ws, size_t ws_size,
                              hipStream_t stream) {
    const float* x   = (const float*)d_in[0];
    const int*   ei  = (const int*)d_in[1];
    const int*   bat = (const int*)d_in[2];
    const float* W1  = (const float*)d_in[3];
    const float* b1  = (const float*)d_in[4];
    const float* W2  = (const float*)d_in[5];
    const float* b2  = (const float*)d_in[6];
    const float* Wg  = (const float*)d_in[7];
    const float* bg  = (const float*)d_in[8];
    const float* Wf  = (const float*)d_in[9];
    const float* bf  = (const float*)d_in[10];
    const float* Wo  = (const float*)d_in[11];
    const float* bo  = (const float*)d_in[12];
    float* out = (float*)d_out;

    // ---- workspace carve-up (all chunks multiple of 16B) ----
    char* p = (char*)d_ws;
    float* dinv     = (float*)p; p += 50048 * 4;
    int*   dcount   = (int*)p;   p += 50048 * 4;
    int*   off      = (int*)p;   p += 50064 * 4;   // N+1 used
    int*   cur      = (int*)p;   p += 50048 * 4;
    int*   partials = (int*)p;   p += 64 * 4;
    int*   csr_src  = (int*)p;   p += (long)N_EDGES * 4;
    float* csr_coef = (float*)p; p += (long)N_EDGES * 4;
    float* aggX     = (float*)p; p += (long)N_NODES * F_IN * 4;   // A@X  [50000,112]
    float* H1       = (float*)p; p += (long)N_NODES * F1 * 4;     // relu((AX)W1+b1)
    float* T2       = (float*)p; p += (long)N_NODES * F2 * 4;     // H1@W2
    float* g        = (float*)p; p += (long)NGRAPH * F2 * 4;

    const int* src = ei;
    const int* dst = ei + N_EDGES;
    const int B = 256;

    // ---- degrees, dinv ----
    k_zero_int<<<(N_NODES + B - 1) / B, B, 0, stream>>>(dcount, N_NODES);
    k_zero_int<<<(N_NODES + B - 1) / B, B, 0, stream>>>(cur, N_NODES);
    k_count_deg<<<(N_EDGES + B - 1) / B, B, 0, stream>>>(dst, dcount, N_EDGES);
    k_dinv<<<(N_NODES + B - 1) / B, B, 0, stream>>>(dcount, dinv, N_NODES);

    // ---- exclusive scan -> off ----
    k_scan1<<<SCAN_BLOCKS, SCAN_CHUNK, 0, stream>>>(dcount, off, partials, N_NODES);
    k_scan2<<<1, 64, 0, stream>>>(partials, off, SCAN_BLOCKS, N_NODES);
    k_scan3<<<SCAN_BLOCKS, SCAN_CHUNK, 0, stream>>>(off, partials, N_NODES);

    // ---- scatter into CSR ----
    k_scatter<<<(N_EDGES + B - 1) / B, B, 0, stream>>>(src, dst, off, cur, dinv,
                                                       csr_src, csr_coef, N_EDGES);

    // ---- layer 1: aggX = A@X ; H1 = relu(aggX@W1 + b1) ----
    k_agg1<<<(N_NODES * 64 + 255) / 256, 256, 0, stream>>>(x, off, csr_src, csr_coef, dinv, aggX);
    dim3 gg1((F1 + 63) / 64, (N_NODES + 63) / 64);
    k_gemm<16, true><<<gg1, 256, 0, stream>>>(aggX, W1, b1, H1, N_NODES, F_IN, F1);

    // ---- layer 2: T2 = H1@W2 ; fused agg+bias+relu+maxpool -> g ----
    dim3 gg2((F2 + 63) / 64, (N_NODES + 63) / 64);
    k_gemm<16, false><<<gg2, 256, 0, stream>>>(H1, W2, nullptr, T2, N_NODES, F1, F2);
    k_zero_f<<<(NGRAPH * F2 + B - 1) / B, B, 0, stream>>>(g, NGRAPH * F2);
    k_agg2_pool<<<(N_NODES * 64 + 255) / 256, 256, 0, stream>>>(T2, off, csr_src, csr_coef,
                                                                dinv, b2, bat, g);

    // ---- MLP head ----
    k_mlp_head<<<NGRAPH, 128, 0, stream>>>(g, Wg, bg, Wf, bf, Wo, bo, out);
}

// Round 4
// 486.678 us; speedup vs baseline: 8.1991x; 1.3418x over previous
//
#include <hip/hip_runtime.h>

#define N_NODES 50000
#define N_EDGES 500000
#define F_IN    112
#define F1      336
#define F2      168
#define NGRAPH  256
#define SCAN_CHUNK 1024
#define SCAN_BLOCKS ((N_NODES + SCAN_CHUNK - 1) / SCAN_CHUNK)   // 49

// ---------------- small utility kernels ----------------
__global__ void k_zero_int(int* p, int n) {
    int i = blockIdx.x * blockDim.x + threadIdx.x;
    if (i < n) p[i] = 0;
}
__global__ void k_count_deg(const int* __restrict__ dst, int* __restrict__ dcount, int e) {
    int i = blockIdx.x * blockDim.x + threadIdx.x;
    if (i < e) atomicAdd(&dcount[dst[i]], 1);
}
__global__ void k_dinv(const int* __restrict__ dcount, float* __restrict__ dinv, int n) {
    int i = blockIdx.x * blockDim.x + threadIdx.x;
    if (i < n) dinv[i] = rsqrtf((float)dcount[i] + 1.0f);   // +1 self-loop
}
// batch is sorted; every graph id present -> per-graph node ranges
__global__ void k_ranges(const int* __restrict__ batch, int* __restrict__ r0,
                         int* __restrict__ r1, int n) {
    int v = blockIdx.x * blockDim.x + threadIdx.x;
    if (v >= n) return;
    int b = batch[v];
    if (v == 0 || batch[v - 1] != b) r0[b] = v;
    if (v == n - 1 || batch[v + 1] != b) r1[b] = v + 1;
}

// ---------------- exclusive scan of dcount -> off ----------------
__global__ __launch_bounds__(SCAN_CHUNK) void k_scan1(const int* __restrict__ dcount,
                                                      int* __restrict__ off,
                                                      int* __restrict__ partials, int n) {
    __shared__ int s[SCAN_CHUNK];
    int t = threadIdx.x;
    int i = blockIdx.x * SCAN_CHUNK + t;
    int val = (i < n) ? dcount[i] : 0;
    s[t] = val;
    __syncthreads();
    for (int d = 1; d < SCAN_CHUNK; d <<= 1) {
        int x = (t >= d) ? s[t - d] : 0;
        __syncthreads();
        s[t] += x;
        __syncthreads();
    }
    if (i < n) off[i] = s[t] - val;
    if (t == SCAN_CHUNK - 1) partials[blockIdx.x] = s[t];
}
__global__ void k_scan2(int* __restrict__ partials, int* __restrict__ off, int nblk, int n) {
    if (threadIdx.x == 0 && blockIdx.x == 0) {
        int run = 0;
        for (int j = 0; j < nblk; ++j) { int p = partials[j]; partials[j] = run; run += p; }
        off[n] = run;
    }
}
__global__ __launch_bounds__(SCAN_CHUNK) void k_scan3(int* __restrict__ off,
                                                      const int* __restrict__ partials, int n) {
    int i = blockIdx.x * SCAN_CHUNK + threadIdx.x;
    if (i < n) off[i] += partials[blockIdx.x];
}

// ---------------- scatter edges into dst-sorted CSR, packed (src, coef) ----------------
__global__ void k_scatter(const int* __restrict__ src, const int* __restrict__ dst,
                          const int* __restrict__ off, int* __restrict__ cur,
                          const float* __restrict__ dinv,
                          int2* __restrict__ csr, int e) {
    int i = blockIdx.x * blockDim.x + threadIdx.x;
    if (i >= e) return;
    int s = src[i], d = dst[i];
    int pos = atomicAdd(&cur[d], 1);
    int2 rec;
    rec.x = s;
    rec.y = __float_as_int(dinv[s] * dinv[d]);
    csr[off[d] + pos] = rec;
}

// ---------------- agg layer 1: outX = A_norm @ X, float2/lane, depth-2 pipeline ----------------
__global__ __launch_bounds__(256) void k_agg1(const float* __restrict__ X,
                                              const int* __restrict__ off,
                                              const int2* __restrict__ csr,
                                              const float* __restrict__ dinv,
                                              float* __restrict__ outX) {
    int gw = (blockIdx.x * 256 + threadIdx.x) >> 6;
    int lane = threadIdx.x & 63;
    if (gw >= N_NODES) return;
    const int v = gw;
    const int NV = F_IN / 2;      // 56 active lanes
    int o0 = off[v], o1 = off[v + 1];
    int n = o1 - o0;
    float di = dinv[v];
    float2 acc = {0.0f, 0.0f};
    if (lane < NV) {
        float2 xv = ((const float2*)(X + (long)v * F_IN))[lane];
        float s2 = di * di;
        acc.x = xv.x * s2; acc.y = xv.y * s2;
    }
    int2 e0, e1; float2 t0 = {0, 0}, t1 = {0, 0};
    if (n > 0) { e0 = csr[o0];     if (lane < NV) t0 = ((const float2*)(X + (long)e0.x * F_IN))[lane]; }
    if (n > 1) { e1 = csr[o0 + 1]; if (lane < NV) t1 = ((const float2*)(X + (long)e1.x * F_IN))[lane]; }
    for (int i = o0 + 2; i < o1; ++i) {
        int2 e2 = csr[i];
        float2 t2 = {0, 0};
        if (lane < NV) t2 = ((const float2*)(X + (long)e2.x * F_IN))[lane];
        float c = __int_as_float(e0.y);
        acc.x += c * t0.x; acc.y += c * t0.y;
        e0 = e1; t0 = t1; e1 = e2; t1 = t2;
    }
    if (n > 1) { float c = __int_as_float(e0.y); acc.x += c * t0.x; acc.y += c * t0.y; e0 = e1; t0 = t1; }
    if (n > 0) { float c = __int_as_float(e0.y); acc.x += c * t0.x; acc.y += c * t0.y; }
    if (lane < NV) ((float2*)(outX + (long)v * F_IN))[lane] = acc;
}

// ---------------- agg layer 2 + bias + relu (NO pool, no atomics) ----------------
__global__ __launch_bounds__(256) void k_agg2(const float* __restrict__ T,
                                              const int* __restrict__ off,
                                              const int2* __restrict__ csr,
                                              const float* __restrict__ dinv,
                                              const float* __restrict__ b2,
                                              float* __restrict__ out2) {
    int gw = (blockIdx.x * 256 + threadIdx.x) >> 6;
    int lane = threadIdx.x & 63;
    if (gw >= N_NODES) return;
    const int v = gw;
    const int NV = F2 / 4;        // 42 active lanes
    int o0 = off[v], o1 = off[v + 1];
    int n = o1 - o0;
    float di = dinv[v];
    float4 acc = {0, 0, 0, 0};
    if (lane < NV) {
        float4 tv = ((const float4*)(T + (long)v * F2))[lane];
        float s2 = di * di;
        acc.x = tv.x * s2; acc.y = tv.y * s2; acc.z = tv.z * s2; acc.w = tv.w * s2;
    }
    int2 e0, e1; float4 t0 = {0, 0, 0, 0}, t1 = {0, 0, 0, 0};
    if (n > 0) { e0 = csr[o0];     if (lane < NV) t0 = ((const float4*)(T + (long)e0.x * F2))[lane]; }
    if (n > 1) { e1 = csr[o0 + 1]; if (lane < NV) t1 = ((const float4*)(T + (long)e1.x * F2))[lane]; }
    for (int i = o0 + 2; i < o1; ++i) {
        int2 e2 = csr[i];
        float4 t2 = {0, 0, 0, 0};
        if (lane < NV) t2 = ((const float4*)(T + (long)e2.x * F2))[lane];
        float c = __int_as_float(e0.y);
        acc.x += c * t0.x; acc.y += c * t0.y; acc.z += c * t0.z; acc.w += c * t0.w;
        e0 = e1; t0 = t1; e1 = e2; t1 = t2;
    }
    if (n > 1) {
        float c = __int_as_float(e0.y);
        acc.x += c * t0.x; acc.y += c * t0.y; acc.z += c * t0.z; acc.w += c * t0.w;
        e0 = e1; t0 = t1;
    }
    if (n > 0) {
        float c = __int_as_float(e0.y);
        acc.x += c * t0.x; acc.y += c * t0.y; acc.z += c * t0.z; acc.w += c * t0.w;
    }
    if (lane < NV) {
        float4 bb = ((const float4*)b2)[lane];
        acc.x = fmaxf(acc.x + bb.x, 0.0f);
        acc.y = fmaxf(acc.y + bb.y, 0.0f);
        acc.z = fmaxf(acc.z + bb.z, 0.0f);
        acc.w = fmaxf(acc.w + bb.w, 0.0f);
        ((float4*)(out2 + (long)v * F2))[lane] = acc;
    }
}

// ---------------- per-graph max pool, zero atomics ----------------
__global__ __launch_bounds__(256) void k_pool(const float* __restrict__ out2,
                                              const int* __restrict__ r0,
                                              const int* __restrict__ r1,
                                              float* __restrict__ g) {
    __shared__ float4 sm[4][F2 / 4];
    int gi = blockIdx.x;
    int slot = threadIdx.x >> 6, lane = threadIdx.x & 63;
    int a = r0[gi], b = r1[gi];
    if (lane < F2 / 4) {
        float4 mx = {0, 0, 0, 0};   // post-relu values >= 0, every graph nonempty
        for (int v = a + slot; v < b; v += 4) {
            float4 t = ((const float4*)(out2 + (long)v * F2))[lane];
            mx.x = fmaxf(mx.x, t.x); mx.y = fmaxf(mx.y, t.y);
            mx.z = fmaxf(mx.z, t.z); mx.w = fmaxf(mx.w, t.w);
        }
        sm[slot][lane] = mx;
    }
    __syncthreads();
    if (slot == 0 && lane < F2 / 4) {
        float4 m0 = sm[0][lane], m1 = sm[1][lane], m2 = sm[2][lane], m3 = sm[3][lane];
        float4 r;
        r.x = fmaxf(fmaxf(m0.x, m1.x), fmaxf(m2.x, m3.x));
        r.y = fmaxf(fmaxf(m0.y, m1.y), fmaxf(m2.y, m3.y));
        r.z = fmaxf(fmaxf(m0.z, m1.z), fmaxf(m2.z, m3.z));
        r.w = fmaxf(fmaxf(m0.w, m1.w), fmaxf(m2.w, m3.w));
        ((float4*)(g + (long)gi * F2))[lane] = r;
    }
}

// ---------------- fp32 GEMM: C = A[M,K]@B[K,N] (+bias,relu) ----------------
// 128x64 tile, TK=16, 8x4 micro-tile, k-major As so all LDS reads are b128.
// Requires K % 16 == 0 and N % 4 == 0 (holds: 112/336 and 336/168).
template<bool FUSE>
__global__ __launch_bounds__(256) void k_gemm(const float* __restrict__ A,
                                              const float* __restrict__ Bm,
                                              const float* __restrict__ bias,
                                              float* __restrict__ C,
                                              int M, int K, int N) {
    __shared__ float As[16][132];   // k-major, pad to 132 (132*4=528B, 16B-aligned rows)
    __shared__ float Bs[16][64];
    const int tid = threadIdx.x;
    const int tx = tid & 15;        // col quad 0..15
    const int ty = tid >> 4;        // row oct  0..15
    const int row0 = blockIdx.y * 128;
    const int col0 = blockIdx.x * 64;

    float acc[8][4] = {};

    for (int k0 = 0; k0 < K; k0 += 16) {
        // stage A: 128 rows x 16 k = 512 float4, 2 per thread; transpose to k-major
        #pragma unroll
        for (int c = 0; c < 2; ++c) {
            int flat = tid + c * 256;            // 0..511
            int m = flat >> 2;                   // 0..127
            int kq = (flat & 3) * 4;             // 0,4,8,12
            int gr = row0 + m;
            float4 a = {0, 0, 0, 0};
            if (gr < M) a = *(const float4*)&A[(long)gr * K + k0 + kq];
            As[kq + 0][m] = a.x; As[kq + 1][m] = a.y;
            As[kq + 2][m] = a.z; As[kq + 3][m] = a.w;
        }
        // stage B: 16 k x 64 n = 1 float4 per thread
        {
            int kk = tid >> 4, nn = (tid & 15) * 4;
            int gc = col0 + nn;
            float4 b = {0, 0, 0, 0};
            if (gc < N) b = *(const float4*)&Bm[(long)(k0 + kk) * N + gc];
            *(float4*)&Bs[kk][nn] = b;
        }
        __syncthreads();
        #pragma unroll
        for (int k = 0; k < 16; ++k) {
            float4 a0 = *(const float4*)&As[k][ty * 8];
            float4 a1 = *(const float4*)&As[k][ty * 8 + 4];
            float4 b4 = *(const float4*)&Bs[k][tx * 4];
            float am[8] = {a0.x, a0.y, a0.z, a0.w, a1.x, a1.y, a1.z, a1.w};
            #pragma unroll
            for (int i = 0; i < 8; ++i) {
                acc[i][0] += am[i] * b4.x;
                acc[i][1] += am[i] * b4.y;
                acc[i][2] += am[i] * b4.z;
                acc[i][3] += am[i] * b4.w;
            }
        }
        __syncthreads();
    }

    int gc = col0 + tx * 4;
    if (gc < N) {
        float4 bb = {0, 0, 0, 0};
        if (FUSE) bb = *(const float4*)&bias[gc];
        #pragma unroll
        for (int i = 0; i < 8; ++i) {
            int gr = row0 + ty * 8 + i;
            if (gr >= M) continue;
            float4 r = {acc[i][0], acc[i][1], acc[i][2], acc[i][3]};
            if (FUSE) {
                r.x = fmaxf(r.x + bb.x, 0.0f);
                r.y = fmaxf(r.y + bb.y, 0.0f);
                r.z = fmaxf(r.z + bb.z, 0.0f);
                r.w = fmaxf(r.w + bb.w, 0.0f);
            }
            *(float4*)&C[(long)gr * N + gc] = r;
        }
    }
}

// ---------------- MLP head ----------------
__global__ __launch_bounds__(128) void k_mlp_head(const float* __restrict__ g,
        const float* __restrict__ Wg, const float* __restrict__ bg,
        const float* __restrict__ Wf, const float* __restrict__ bf,
        const float* __restrict__ Wo, const float* __restrict__ bo,
        float* __restrict__ out) {
    __shared__ float s0[F2];
    __shared__ float s1[84];
    __shared__ float s2[42];
    int gi = blockIdx.x;
    int t = threadIdx.x;
    for (int i = t; i < F2; i += blockDim.x) s0[i] = g[(long)gi * F2 + i];
    __syncthreads();
    if (t < 84) {
        float a = bg[t];
        #pragma unroll 4
        for (int k = 0; k < F2; ++k) a += s0[k] * Wg[k * 84 + t];
        s1[t] = fmaxf(a, 0.0f);
    }
    __syncthreads();
    if (t < 42) {
        float a = bf[t];
        #pragma unroll 4
        for (int k = 0; k < 84; ++k) a += s1[k] * Wf[k * 42 + t];
        s2[t] = fmaxf(a, 0.0f);
    }
    __syncthreads();
    if (t == 0) {
        float a = bo[0];
        for (int k = 0; k < 42; ++k) a += s2[k] * Wo[k];
        out[gi] = a;
    }
}

extern "C" void kernel_launch(void* const* d_in, const int* in_sizes, int n_in,
                              void* d_out, int out_size, void* d_ws, size_t ws_size,
                              hipStream_t stream) {
    const float* x   = (const float*)d_in[0];
    const int*   ei  = (const int*)d_in[1];
    const int*   bat = (const int*)d_in[2];
    const float* W1  = (const float*)d_in[3];
    const float* b1  = (const float*)d_in[4];
    const float* W2  = (const float*)d_in[5];
    const float* b2  = (const float*)d_in[6];
    const float* Wg  = (const float*)d_in[7];
    const float* bg  = (const float*)d_in[8];
    const float* Wf  = (const float*)d_in[9];
    const float* bf  = (const float*)d_in[10];
    const float* Wo  = (const float*)d_in[11];
    const float* bo  = (const float*)d_in[12];
    float* out = (float*)d_out;

    // ---- workspace carve-up ----
    char* p = (char*)d_ws;
    float* dinv     = (float*)p; p += 50048 * 4;
    int*   dcount   = (int*)p;   p += 50048 * 4;
    int*   off      = (int*)p;   p += 50064 * 4;   // N+1 used
    int*   cur      = (int*)p;   p += 50048 * 4;
    int*   partials = (int*)p;   p += 64 * 4;
    int*   rng0     = (int*)p;   p += 256 * 4;
    int*   rng1     = (int*)p;   p += 256 * 4;
    int2*  csr      = (int2*)p;  p += (long)N_EDGES * 8;
    float* aggX     = (float*)p; p += (long)N_NODES * F_IN * 4;
    float* H1       = (float*)p; p += (long)N_NODES * F1 * 4;
    float* T2       = (float*)p; p += (long)N_NODES * F2 * 4;
    float* out2     = (float*)p; p += (long)N_NODES * F2 * 4;
    float* g        = (float*)p; p += (long)NGRAPH * F2 * 4;

    const int* src = ei;
    const int* dst = ei + N_EDGES;
    const int B = 256;

    // ---- degrees, dinv, ranges ----
    k_zero_int<<<(N_NODES + B - 1) / B, B, 0, stream>>>(dcount, N_NODES);
    k_zero_int<<<(N_NODES + B - 1) / B, B, 0, stream>>>(cur, N_NODES);
    k_count_deg<<<(N_EDGES + B - 1) / B, B, 0, stream>>>(dst, dcount, N_EDGES);
    k_dinv<<<(N_NODES + B - 1) / B, B, 0, stream>>>(dcount, dinv, N_NODES);
    k_ranges<<<(N_NODES + B - 1) / B, B, 0, stream>>>(bat, rng0, rng1, N_NODES);

    // ---- scan -> off ----
    k_scan1<<<SCAN_BLOCKS, SCAN_CHUNK, 0, stream>>>(dcount, off, partials, N_NODES);
    k_scan2<<<1, 64, 0, stream>>>(partials, off, SCAN_BLOCKS, N_NODES);
    k_scan3<<<SCAN_BLOCKS, SCAN_CHUNK, 0, stream>>>(off, partials, N_NODES);

    // ---- scatter CSR ----
    k_scatter<<<(N_EDGES + B - 1) / B, B, 0, stream>>>(src, dst, off, cur, dinv, csr, N_EDGES);

    // ---- layer 1 ----
    k_agg1<<<(N_NODES * 64 + 255) / 256, 256, 0, stream>>>(x, off, csr, dinv, aggX);
    dim3 gg1((F1 + 63) / 64, (N_NODES + 127) / 128);
    k_gemm<true><<<gg1, 256, 0, stream>>>(aggX, W1, b1, H1, N_NODES, F_IN, F1);

    // ---- layer 2 ----
    dim3 gg2((F2 + 63) / 64, (N_NODES + 127) / 128);
    k_gemm<false><<<gg2, 256, 0, stream>>>(H1, W2, nullptr, T2, N_NODES, F1, F2);
    k_agg2<<<(N_NODES * 64 + 255) / 256, 256, 0, stream>>>(T2, off, csr, dinv, b2, out2);

    // ---- pool + head ----
    k_pool<<<NGRAPH, 256, 0, stream>>>(out2, rng0, rng1, g);
    k_mlp_head<<<NGRAPH, 128, 0, stream>>>(g, Wg, bg, Wf, bf, Wo, bo, out);
}

// Round 5
// 430.238 us; speedup vs baseline: 9.2747x; 1.1312x over previous
//
#include <hip/hip_runtime.h>

#define N_NODES 50000
#define MPAD    50048            // 391 * 128
#define N_EDGES 500000
#define F_IN    112
#define K1P     128              // F_IN padded to 32-multiple
#define F1      336
#define K2P     352              // F1 padded to 32-multiple
#define F2      168
#define NGRAPH  256
#define SCAN_CHUNK 1024
#define SCAN_BLOCKS ((N_NODES + SCAN_CHUNK - 1) / SCAN_CHUNK)   // 49

typedef __attribute__((ext_vector_type(8))) __bf16 bf16x8;
typedef __attribute__((ext_vector_type(4))) float f32x4;
typedef unsigned short ushort_t;

__device__ __forceinline__ ushort_t bf16_rne(float x) {
    unsigned u = __float_as_uint(x);
    unsigned r = u + 0x7FFF + ((u >> 16) & 1);
    return (ushort_t)(r >> 16);
}
__device__ __forceinline__ float bf16_tof(ushort_t h) {
    return __uint_as_float(((unsigned)h) << 16);
}

// ---------------- small utility kernels ----------------
__global__ void k_zero_int(int* p, int n) {
    int i = blockIdx.x * blockDim.x + threadIdx.x;
    if (i < n) p[i] = 0;
}
__global__ void k_count_deg(const int* __restrict__ dst, int* __restrict__ dcount, int e) {
    int i = blockIdx.x * blockDim.x + threadIdx.x;
    if (i < e) atomicAdd(&dcount[dst[i]], 1);
}
__global__ void k_dinv(const int* __restrict__ dcount, float* __restrict__ dinv, int n) {
    int i = blockIdx.x * blockDim.x + threadIdx.x;
    if (i < n) dinv[i] = rsqrtf((float)dcount[i] + 1.0f);   // +1 self-loop
}
__global__ void k_ranges(const int* __restrict__ batch, int* __restrict__ r0,
                         int* __restrict__ r1, int n) {
    int v = blockIdx.x * blockDim.x + threadIdx.x;
    if (v >= n) return;
    int b = batch[v];
    if (v == 0 || batch[v - 1] != b) r0[b] = v;
    if (v == n - 1 || batch[v + 1] != b) r1[b] = v + 1;
}

// ---------------- exclusive scan of dcount -> off ----------------
__global__ __launch_bounds__(SCAN_CHUNK) void k_scan1(const int* __restrict__ dcount,
                                                      int* __restrict__ off,
                                                      int* __restrict__ partials, int n) {
    __shared__ int s[SCAN_CHUNK];
    int t = threadIdx.x;
    int i = blockIdx.x * SCAN_CHUNK + t;
    int val = (i < n) ? dcount[i] : 0;
    s[t] = val;
    __syncthreads();
    for (int d = 1; d < SCAN_CHUNK; d <<= 1) {
        int x = (t >= d) ? s[t - d] : 0;
        __syncthreads();
        s[t] += x;
        __syncthreads();
    }
    if (i < n) off[i] = s[t] - val;
    if (t == SCAN_CHUNK - 1) partials[blockIdx.x] = s[t];
}
__global__ void k_scan2(int* __restrict__ partials, int* __restrict__ off, int nblk, int n) {
    if (threadIdx.x == 0 && blockIdx.x == 0) {
        int run = 0;
        for (int j = 0; j < nblk; ++j) { int p = partials[j]; partials[j] = run; run += p; }
        off[n] = run;
    }
}
__global__ __launch_bounds__(SCAN_CHUNK) void k_scan3(int* __restrict__ off,
                                                      const int* __restrict__ partials, int n) {
    int i = blockIdx.x * SCAN_CHUNK + threadIdx.x;
    if (i < n) off[i] += partials[blockIdx.x];
}

// ---------------- scatter edges into dst-sorted CSR, packed (src, coef) ----------------
__global__ void k_scatter(const int* __restrict__ src, const int* __restrict__ dst,
                          const int* __restrict__ off, int* __restrict__ cur,
                          const float* __restrict__ dinv,
                          int2* __restrict__ csr, int e) {
    int i = blockIdx.x * blockDim.x + threadIdx.x;
    if (i >= e) return;
    int s = src[i], d = dst[i];
    int pos = atomicAdd(&cur[d], 1);
    int2 rec;
    rec.x = s;
    rec.y = __float_as_int(dinv[s] * dinv[d]);
    csr[off[d] + pos] = rec;
}

// ---------------- weight transpose + bf16 split: W[K,N] -> Wh/Wl[NP][KP] ----------------
template<int K, int N, int KP, int NP>
__global__ void k_cvtW(const float* __restrict__ W, ushort_t* __restrict__ Wh,
                       ushort_t* __restrict__ Wl) {
    int idx = blockIdx.x * 256 + threadIdx.x;
    if (idx >= NP * KP) return;
    int n = idx / KP, k = idx % KP;
    float v = (n < N && k < K) ? W[k * N + n] : 0.0f;
    ushort_t h = bf16_rne(v);
    ushort_t l = bf16_rne(v - bf16_tof(h));
    Wh[idx] = h;
    Wl[idx] = l;
}

// ---------------- agg layer 1: A_norm @ X -> bf16 hi/lo planes [MPAD][K1P] ----------------
__global__ __launch_bounds__(256) void k_agg1(const float* __restrict__ X,
                                              const int* __restrict__ off,
                                              const int2* __restrict__ csr,
                                              const float* __restrict__ dinv,
                                              ushort_t* __restrict__ aXh,
                                              ushort_t* __restrict__ aXl) {
    int gw = (blockIdx.x * 256 + threadIdx.x) >> 6;
    int lane = threadIdx.x & 63;
    if (gw >= N_NODES) return;
    const int v = gw;
    const int NV = F_IN / 2;      // 56 active lanes
    int o0 = off[v], o1 = off[v + 1];
    int n = o1 - o0;
    float di = dinv[v];
    float2 acc = {0.0f, 0.0f};
    if (lane < NV) {
        float2 xv = ((const float2*)(X + (long)v * F_IN))[lane];
        float s2 = di * di;
        acc.x = xv.x * s2; acc.y = xv.y * s2;
    }
    int2 e0, e1; float2 t0 = {0, 0}, t1 = {0, 0};
    if (n > 0) { e0 = csr[o0];     if (lane < NV) t0 = ((const float2*)(X + (long)e0.x * F_IN))[lane]; }
    if (n > 1) { e1 = csr[o0 + 1]; if (lane < NV) t1 = ((const float2*)(X + (long)e1.x * F_IN))[lane]; }
    for (int i = o0 + 2; i < o1; ++i) {
        int2 e2 = csr[i];
        float2 t2 = {0, 0};
        if (lane < NV) t2 = ((const float2*)(X + (long)e2.x * F_IN))[lane];
        float c = __int_as_float(e0.y);
        acc.x += c * t0.x; acc.y += c * t0.y;
        e0 = e1; t0 = t1; e1 = e2; t1 = t2;
    }
    if (n > 1) { float c = __int_as_float(e0.y); acc.x += c * t0.x; acc.y += c * t0.y; e0 = e1; t0 = t1; }
    if (n > 0) { float c = __int_as_float(e0.y); acc.x += c * t0.x; acc.y += c * t0.y; }
    // split write: cols 2*lane, 2*lane+1 ; lanes 56..63 write zero pad (cols 112..127)
    unsigned vh = 0, vl = 0;
    if (lane < NV) {
        ushort_t h0 = bf16_rne(acc.x); ushort_t l0 = bf16_rne(acc.x - bf16_tof(h0));
        ushort_t h1 = bf16_rne(acc.y); ushort_t l1 = bf16_rne(acc.y - bf16_tof(h1));
        vh = (unsigned)h0 | ((unsigned)h1 << 16);
        vl = (unsigned)l0 | ((unsigned)l1 << 16);
    }
    ((unsigned*)(aXh + (long)v * K1P))[lane] = vh;
    ((unsigned*)(aXl + (long)v * K1P))[lane] = vl;
}

// ---------------- MFMA split-bf16 GEMM: C = A[M,KP] @ Bt[N,KP]^T ----------------
// 128x64 block tile, 4 waves (2x2), each wave 64x32 via 16x16x32 MFMA.
// EPI==1: C -> bf16 hi/lo planes width CW, relu(acc+bias) for col<Nreal, 0 for Nreal<=col<CW
// EPI==2: C -> fp32, width Nreal
template<int KP, int EPI>
__global__ __launch_bounds__(256) void k_gemm_mfma(
        const ushort_t* __restrict__ Ah, const ushort_t* __restrict__ Al,
        const ushort_t* __restrict__ Bh, const ushort_t* __restrict__ Bl,
        const float* __restrict__ bias,
        ushort_t* __restrict__ Ch, ushort_t* __restrict__ Cl,
        float* __restrict__ Cf,
        int M, int Nreal, int CW) {
    __shared__ ushort_t AsH[128][40];
    __shared__ ushort_t AsL[128][40];
    __shared__ ushort_t BsH[64][40];
    __shared__ ushort_t BsL[64][40];
    const int tid = threadIdx.x;
    const int row0 = blockIdx.y * 128;
    const int col0 = blockIdx.x * 64;
    const int w  = tid >> 6, l = tid & 63;
    const int wm = w >> 1, wn = w & 1;
    const int lm = l & 15, lq = l >> 4;

    f32x4 acc[4][2];
    #pragma unroll
    for (int i = 0; i < 4; ++i)
        #pragma unroll
        for (int j = 0; j < 2; ++j) acc[i][j] = (f32x4){0.f, 0.f, 0.f, 0.f};

    const int arow  = tid >> 2;         // 0..63
    const int akoff = (tid & 3) * 8;    // 0,8,16,24

    for (int k0 = 0; k0 < KP; k0 += 32) {
        *(int4*)&AsH[arow][akoff]      = *(const int4*)&Ah[(long)(row0 + arow) * KP + k0 + akoff];
        *(int4*)&AsH[arow + 64][akoff] = *(const int4*)&Ah[(long)(row0 + arow + 64) * KP + k0 + akoff];
        *(int4*)&AsL[arow][akoff]      = *(const int4*)&Al[(long)(row0 + arow) * KP + k0 + akoff];
        *(int4*)&AsL[arow + 64][akoff] = *(const int4*)&Al[(long)(row0 + arow + 64) * KP + k0 + akoff];
        *(int4*)&BsH[arow][akoff]      = *(const int4*)&Bh[(long)(col0 + arow) * KP + k0 + akoff];
        *(int4*)&BsL[arow][akoff]      = *(const int4*)&Bl[(long)(col0 + arow) * KP + k0 + akoff];
        __syncthreads();

        bf16x8 afh[4], afl[4], bfh[2], bfl[2];
        #pragma unroll
        for (int ms = 0; ms < 4; ++ms) {
            afh[ms] = *(const bf16x8*)&AsH[wm * 64 + ms * 16 + lm][lq * 8];
            afl[ms] = *(const bf16x8*)&AsL[wm * 64 + ms * 16 + lm][lq * 8];
        }
        #pragma unroll
        for (int ns = 0; ns < 2; ++ns) {
            bfh[ns] = *(const bf16x8*)&BsH[wn * 32 + ns * 16 + lm][lq * 8];
            bfl[ns] = *(const bf16x8*)&BsL[wn * 32 + ns * 16 + lm][lq * 8];
        }
        #pragma unroll
        for (int ms = 0; ms < 4; ++ms)
            #pragma unroll
            for (int ns = 0; ns < 2; ++ns) {
                acc[ms][ns] = __builtin_amdgcn_mfma_f32_16x16x32_bf16(afh[ms], bfh[ns], acc[ms][ns], 0, 0, 0);
                acc[ms][ns] = __builtin_amdgcn_mfma_f32_16x16x32_bf16(afh[ms], bfl[ns], acc[ms][ns], 0, 0, 0);
                acc[ms][ns] = __builtin_amdgcn_mfma_f32_16x16x32_bf16(afl[ms], bfh[ns], acc[ms][ns], 0, 0, 0);
            }
        __syncthreads();
    }

    // epilogue: C/D layout col=lane&15, row=(lane>>4)*4+i  [m89/m91 verified]
    #pragma unroll
    for (int ms = 0; ms < 4; ++ms) {
        int R = row0 + wm * 64 + ms * 16 + lq * 4;
        #pragma unroll
        for (int ns = 0; ns < 2; ++ns) {
            int col = col0 + wn * 32 + ns * 16 + lm;
            if (EPI == 1) {
                if (col < CW) {
                    float bb = (col < Nreal) ? bias[col] : 0.0f;
                    #pragma unroll
                    for (int i = 0; i < 4; ++i) {
                        int row = R + i;
                        if (row < M) {
                            float r = (col < Nreal) ? fmaxf(acc[ms][ns][i] + bb, 0.0f) : 0.0f;
                            ushort_t h = bf16_rne(r);
                            ushort_t lo = bf16_rne(r - bf16_tof(h));
                            Ch[(long)row * CW + col] = h;
                            Cl[(long)row * CW + col] = lo;
                        }
                    }
                }
            } else {
                if (col < Nreal) {
                    #pragma unroll
                    for (int i = 0; i < 4; ++i) {
                        int row = R + i;
                        if (row < M) Cf[(long)row * Nreal + col] = acc[ms][ns][i];
                    }
                }
            }
        }
    }
}

// ---------------- agg layer 2 + bias + relu (no atomics) ----------------
__global__ __launch_bounds__(256) void k_agg2(const float* __restrict__ T,
                                              const int* __restrict__ off,
                                              const int2* __restrict__ csr,
                                              const float* __restrict__ dinv,
                                              const float* __restrict__ b2,
                                              float* __restrict__ out2) {
    int gw = (blockIdx.x * 256 + threadIdx.x) >> 6;
    int lane = threadIdx.x & 63;
    if (gw >= N_NODES) return;
    const int v = gw;
    const int NV = F2 / 4;        // 42 active lanes
    int o0 = off[v], o1 = off[v + 1];
    int n = o1 - o0;
    float di = dinv[v];
    float4 acc = {0, 0, 0, 0};
    if (lane < NV) {
        float4 tv = ((const float4*)(T + (long)v * F2))[lane];
        float s2 = di * di;
        acc.x = tv.x * s2; acc.y = tv.y * s2; acc.z = tv.z * s2; acc.w = tv.w * s2;
    }
    int2 e0, e1; float4 t0 = {0, 0, 0, 0}, t1 = {0, 0, 0, 0};
    if (n > 0) { e0 = csr[o0];     if (lane < NV) t0 = ((const float4*)(T + (long)e0.x * F2))[lane]; }
    if (n > 1) { e1 = csr[o0 + 1]; if (lane < NV) t1 = ((const float4*)(T + (long)e1.x * F2))[lane]; }
    for (int i = o0 + 2; i < o1; ++i) {
        int2 e2 = csr[i];
        float4 t2 = {0, 0, 0, 0};
        if (lane < NV) t2 = ((const float4*)(T + (long)e2.x * F2))[lane];
        float c = __int_as_float(e0.y);
        acc.x += c * t0.x; acc.y += c * t0.y; acc.z += c * t0.z; acc.w += c * t0.w;
        e0 = e1; t0 = t1; e1 = e2; t1 = t2;
    }
    if (n > 1) {
        float c = __int_as_float(e0.y);
        acc.x += c * t0.x; acc.y += c * t0.y; acc.z += c * t0.z; acc.w += c * t0.w;
        e0 = e1; t0 = t1;
    }
    if (n > 0) {
        float c = __int_as_float(e0.y);
        acc.x += c * t0.x; acc.y += c * t0.y; acc.z += c * t0.z; acc.w += c * t0.w;
    }
    if (lane < NV) {
        float4 bb = ((const float4*)b2)[lane];
        acc.x = fmaxf(acc.x + bb.x, 0.0f);
        acc.y = fmaxf(acc.y + bb.y, 0.0f);
        acc.z = fmaxf(acc.z + bb.z, 0.0f);
        acc.w = fmaxf(acc.w + bb.w, 0.0f);
        ((float4*)(out2 + (long)v * F2))[lane] = acc;
    }
}

// ---------------- per-graph max pool ----------------
__global__ __launch_bounds__(256) void k_pool(const float* __restrict__ out2,
                                              const int* __restrict__ r0,
                                              const int* __restrict__ r1,
                                              float* __restrict__ g) {
    __shared__ float4 sm[4][F2 / 4];
    int gi = blockIdx.x;
    int slot = threadIdx.x >> 6, lane = threadIdx.x & 63;
    int a = r0[gi], b = r1[gi];
    if (lane < F2 / 4) {
        float4 mx = {0, 0, 0, 0};
        for (int v = a + slot; v < b; v += 4) {
            float4 t = ((const float4*)(out2 + (long)v * F2))[lane];
            mx.x = fmaxf(mx.x, t.x); mx.y = fmaxf(mx.y, t.y);
            mx.z = fmaxf(mx.z, t.z); mx.w = fmaxf(mx.w, t.w);
        }
        sm[slot][lane] = mx;
    }
    __syncthreads();
    if (slot == 0 && lane < F2 / 4) {
        float4 m0 = sm[0][lane], m1 = sm[1][lane], m2 = sm[2][lane], m3 = sm[3][lane];
        float4 r;
        r.x = fmaxf(fmaxf(m0.x, m1.x), fmaxf(m2.x, m3.x));
        r.y = fmaxf(fmaxf(m0.y, m1.y), fmaxf(m2.y, m3.y));
        r.z = fmaxf(fmaxf(m0.z, m1.z), fmaxf(m2.z, m3.z));
        r.w = fmaxf(fmaxf(m0.w, m1.w), fmaxf(m2.w, m3.w));
        ((float4*)(g + (long)gi * F2))[lane] = r;
    }
}

// ---------------- MLP head ----------------
__global__ __launch_bounds__(128) void k_mlp_head(const float* __restrict__ g,
        const float* __restrict__ Wg, const float* __restrict__ bg,
        const float* __restrict__ Wf, const float* __restrict__ bf,
        const float* __restrict__ Wo, const float* __restrict__ bo,
        float* __restrict__ out) {
    __shared__ float s0[F2];
    __shared__ float s1[84];
    __shared__ float s2[42];
    int gi = blockIdx.x;
    int t = threadIdx.x;
    for (int i = t; i < F2; i += blockDim.x) s0[i] = g[(long)gi * F2 + i];
    __syncthreads();
    if (t < 84) {
        float a = bg[t];
        #pragma unroll 4
        for (int k = 0; k < F2; ++k) a += s0[k] * Wg[k * 84 + t];
        s1[t] = fmaxf(a, 0.0f);
    }
    __syncthreads();
    if (t < 42) {
        float a = bf[t];
        #pragma unroll 4
        for (int k = 0; k < 84; ++k) a += s1[k] * Wf[k * 42 + t];
        s2[t] = fmaxf(a, 0.0f);
    }
    __syncthreads();
    if (t == 0) {
        float a = bo[0];
        for (int k = 0; k < 42; ++k) a += s2[k] * Wo[k];
        out[gi] = a;
    }
}

extern "C" void kernel_launch(void* const* d_in, const int* in_sizes, int n_in,
                              void* d_out, int out_size, void* d_ws, size_t ws_size,
                              hipStream_t stream) {
    const float* x   = (const float*)d_in[0];
    const int*   ei  = (const int*)d_in[1];
    const int*   bat = (const int*)d_in[2];
    const float* W1  = (const float*)d_in[3];
    const float* b1  = (const float*)d_in[4];
    const float* W2  = (const float*)d_in[5];
    const float* b2  = (const float*)d_in[6];
    const float* Wg  = (const float*)d_in[7];
    const float* bg  = (const float*)d_in[8];
    const float* Wf  = (const float*)d_in[9];
    const float* bf  = (const float*)d_in[10];
    const float* Wo  = (const float*)d_in[11];
    const float* bo  = (const float*)d_in[12];
    float* out = (float*)d_out;

    // ---- workspace carve-up (every chunk 16B-aligned) ----
    char* p = (char*)d_ws;
    float* dinv     = (float*)p; p += 50048 * 4;
    int*   dcount   = (int*)p;   p += 50048 * 4;
    int*   off      = (int*)p;   p += 50064 * 4;
    int*   cur      = (int*)p;   p += 50048 * 4;
    int*   partials = (int*)p;   p += 64 * 4;
    int*   rng0     = (int*)p;   p += 256 * 4;
    int*   rng1     = (int*)p;   p += 256 * 4;
    int2*  csr      = (int2*)p;  p += (long)N_EDGES * 8;
    ushort_t* aXh   = (ushort_t*)p; p += (long)MPAD * K1P * 2;   // 12.8 MB
    ushort_t* aXl   = (ushort_t*)p; p += (long)MPAD * K1P * 2;
    ushort_t* w1th  = (ushort_t*)p; p += (long)384 * K1P * 2;    // [384][128]
    ushort_t* w1tl  = (ushort_t*)p; p += (long)384 * K1P * 2;
    ushort_t* w2th  = (ushort_t*)p; p += (long)192 * K2P * 2;    // [192][352]
    ushort_t* w2tl  = (ushort_t*)p; p += (long)192 * K2P * 2;
    ushort_t* h1h   = (ushort_t*)p; p += (long)MPAD * K2P * 2;   // 35.2 MB
    ushort_t* h1l   = (ushort_t*)p; p += (long)MPAD * K2P * 2;
    float* T2       = (float*)p; p += (long)N_NODES * F2 * 4;
    float* out2     = (float*)p; p += (long)N_NODES * F2 * 4;
    float* g        = (float*)p; p += (long)NGRAPH * F2 * 4;

    const int* src = ei;
    const int* dst = ei + N_EDGES;
    const int B = 256;

    // ---- degrees, dinv, ranges ----
    k_zero_int<<<(N_NODES + B - 1) / B, B, 0, stream>>>(dcount, N_NODES);
    k_zero_int<<<(N_NODES + B - 1) / B, B, 0, stream>>>(cur, N_NODES);
    k_count_deg<<<(N_EDGES + B - 1) / B, B, 0, stream>>>(dst, dcount, N_EDGES);
    k_dinv<<<(N_NODES + B - 1) / B, B, 0, stream>>>(dcount, dinv, N_NODES);
    k_ranges<<<(N_NODES + B - 1) / B, B, 0, stream>>>(bat, rng0, rng1, N_NODES);

    // ---- scan -> off ----
    k_scan1<<<SCAN_BLOCKS, SCAN_CHUNK, 0, stream>>>(dcount, off, partials, N_NODES);
    k_scan2<<<1, 64, 0, stream>>>(partials, off, SCAN_BLOCKS, N_NODES);
    k_scan3<<<SCAN_BLOCKS, SCAN_CHUNK, 0, stream>>>(off, partials, N_NODES);

    // ---- scatter CSR ----
    k_scatter<<<(N_EDGES + B - 1) / B, B, 0, stream>>>(src, dst, off, cur, dinv, csr, N_EDGES);

    // ---- weight transpose+split ----
    k_cvtW<F_IN, F1, K1P, 384><<<(384 * K1P + 255) / 256, 256, 0, stream>>>(W1, w1th, w1tl);
    k_cvtW<F1, F2, K2P, 192><<<(192 * K2P + 255) / 256, 256, 0, stream>>>(W2, w2th, w2tl);

    // ---- layer 1: agg (-> bf16 planes), MFMA gemm (-> H1 planes, bias+relu fused) ----
    k_agg1<<<(N_NODES * 64 + 255) / 256, 256, 0, stream>>>(x, off, csr, dinv, aXh, aXl);
    dim3 gg1(6, MPAD / 128);   // N blocks: 384/64 ; M blocks: 391
    k_gemm_mfma<K1P, 1><<<gg1, 256, 0, stream>>>(aXh, aXl, w1th, w1tl, b1,
                                                 h1h, h1l, nullptr, N_NODES, F1, K2P);

    // ---- layer 2: MFMA gemm (-> T2 fp32), agg+bias+relu ----
    dim3 gg2(3, MPAD / 128);   // 192/64 ; 391
    k_gemm_mfma<K2P, 2><<<gg2, 256, 0, stream>>>(h1h, h1l, w2th, w2tl, nullptr,
                                                 nullptr, nullptr, T2, N_NODES, F2, 0);
    k_agg2<<<(N_NODES * 64 + 255) / 256, 256, 0, stream>>>(T2, off, csr, dinv, b2, out2);

    // ---- pool + head ----
    k_pool<<<NGRAPH, 256, 0, stream>>>(out2, rng0, rng1, g);
    k_mlp_head<<<NGRAPH, 128, 0, stream>>>(g, Wg, bg, Wf, bf, Wo, bo, out);
}